// Round 2
// baseline (965.661 us; speedup 1.0000x reference)
//
#include <hip/hip_runtime.h>
#include <hip/hip_bf16.h>

typedef __bf16 bf16_t;
typedef __bf16 bf16x8 __attribute__((ext_vector_type(8)));
typedef float f32x4 __attribute__((ext_vector_type(4)));

#define LDK 520   // X rows: [hi 256 | lo 256] + 8 pad (byte stride 1040 = 16*65)
#define LDT 136   // theta/y rows (128 + 8)
#define LDF 264   // F rows (256 + 8)
#define LDS_S 260 // S rows fp32
#define LDQ 34    // wyT rows fp32

__device__ __forceinline__ float ldin(const void* p, long i, int isbf) {
  if (isbf) {
    unsigned short u = ((const unsigned short*)p)[i];
    unsigned int w = ((unsigned int)u) << 16;
    float f; __builtin_memcpy(&f, &w, 4); return f;
  }
  return ((const float*)p)[i];
}

__device__ __forceinline__ bf16_t f2b(float f) {
  unsigned int u; __builtin_memcpy(&u, &f, 4);
  u += 0x7FFFu + ((u >> 16) & 1u);
  unsigned short h = (unsigned short)(u >> 16);
  bf16_t r; __builtin_memcpy(&r, &h, 2); return r;
}

__device__ __forceinline__ float b2f(bf16_t b) {
  unsigned short h; __builtin_memcpy(&h, &b, 2);
  unsigned int u = ((unsigned int)h) << 16;
  float f; __builtin_memcpy(&f, &u, 4); return f;
}

// D(16x16) += A(16xK) * B(Kx16). A: LDS rows [m][K] (ptr pre-offset to row m0+ln).
// B: BT rows [n][K] (ptr pre-offset to row n0+ln). kq=(lane>>4)*8.
// D: n=lane&15, m=(lane>>4)*4+reg.
__device__ __forceinline__ f32x4 mm_acc(const bf16_t* A, const bf16_t* B, int kq,
                                        int K, f32x4 acc) {
  for (int k = 0; k < K; k += 32) {
    bf16x8 a = *(const bf16x8*)(A + k + kq);
    bf16x8 b = *(const bf16x8*)(B + k + kq);
    acc = __builtin_amdgcn_mfma_f32_16x16x32_bf16(a, b, acc, 0, 0, 0);
  }
  return acc;
}

// ---- dtype detector ----
__global__ void kdetect(const unsigned int* x, int* flag) {
  __shared__ int cnt;
  if (threadIdx.x == 0) cnt = 0;
  __syncthreads();
  int local = 0;
  for (int k = 0; k < 4; ++k) {
    unsigned int u = x[threadIdx.x * 4 + k];
    unsigned int e = (u >> 7) & 0xFFu;   // exponent field if low half is bf16
    if (e >= 116u && e <= 133u) local++;
  }
  atomicAdd(&cnt, local);
  __syncthreads();
  if (threadIdx.x == 0) *flag = (cnt > 512) ? 1 : 0;
}

// ---- K0: weights (doubled rows [w|w] for K=512 split path) + BN folding ----
__global__ void k0(const void* thw_f, const void* phw, const void* gw, const void* ww_f,
                   const void* wb, const void* gma, const void* bta, const void* mean,
                   const void* var, bf16_t* thw2, bf16_t* wpg2, bf16_t* ww,
                   float* sc, float* sh, const int* flag) {
  int isbf = *flag;
  int i = blockIdx.x * 256 + threadIdx.x;   // 512 blocks -> 131072 threads
  { // wpg2: 256 rows x 512
    int o = i >> 9, c = i & 255;
    float v = (o < 128) ? ldin(phw, o * 256 + c, isbf)
                        : ldin(gw, (o - 128) * 256 + c, isbf);
    wpg2[i] = f2b(v);
  }
  if (i < 65536) { // thw2: 128 rows x 512
    int o = i >> 9, c = i & 255;
    thw2[i] = f2b(ldin(thw_f, o * 256 + c, isbf));
  }
  if (i < 32768) ww[i] = f2b(ldin(ww_f, i, isbf));
  if (i < 256) {
    float s = ldin(gma, i, isbf) * rsqrtf(ldin(var, i, isbf) + 1e-5f);
    sc[i] = s;
    sh[i] = (ldin(wb, i, isbf) - ldin(mean, i, isbf)) * s + ldin(bta, i, isbf);
  }
}

// ---- K1: phi/g conv + register-level 2x2 maxpool; phi stored hi+lo ----
__global__ __launch_bounds__(256) void k1(const void* xin, const bf16_t* wpg2,
    const void* phib, const void* gb, bf16_t* phiTh, bf16_t* phiTl, bf16_t* gT,
    const int* flag) {
  int isbf = *flag;
  int wg = blockIdx.x;          // 128*16
  int tile = wg >> 4;
  int j = wg & 15;              // pooled row within tile
  int bi = tile >> 4, t16 = tile & 15;
  int ty = t16 >> 2, tx = t16 & 3;
  long xbase = ((long)bi * 256) * 16384 + (long)(ty * 32 + 2 * j) * 128 + tx * 32;

  __shared__ __align__(16) bf16_t sX[32 * LDK];

  int tid = threadIdx.x, lane = tid & 63, wv = tid >> 6;
  int qd = lane >> 4, ln = lane & 15, kq = qd * 8;
  int Keff = isbf ? 256 : 512;

  f32x4 acc[2][8];
  for (int ph = 0; ph < 2; ++ph) {
    if (ph) __syncthreads();    // prior MFMA reads done before restage
    for (int i = tid; i < 32 * 256; i += 256) {
      int c = i >> 5, col = i & 31;
      float v = ldin(xin, xbase + ph * 128 + (long)c * 16384 + col, isbf);
      bf16_t hi = f2b(v);
      sX[col * LDK + c] = hi;
      if (!isbf) sX[col * LDK + 256 + c] = f2b(v - b2f(hi));
    }
    __syncthreads();
    #pragma unroll
    for (int t = 0; t < 8; ++t) {
      int tt = wv + 4 * t, ms = tt >> 4, ns = tt & 15;
      f32x4 z = {0.f, 0.f, 0.f, 0.f};
      acc[ph][t] = mm_acc(sX + (ms * 16 + ln) * LDK, wpg2 + (ns * 16 + ln) * 512,
                          kq, Keff, z);
    }
  }
  // register maxpool: col pairs = reg pairs (r,r+1); row pair = ph 0/1
  #pragma unroll
  for (int t = 0; t < 8; ++t) {
    int tt = wv + 4 * t, ms = tt >> 4, ns = tt & 15;
    int o = ns * 16 + ln;
    #pragma unroll
    for (int r = 0; r < 4; r += 2) {
      float v = fmaxf(fmaxf(acc[0][t][r], acc[0][t][r + 1]),
                      fmaxf(acc[1][t][r], acc[1][t][r + 1]));
      int cp = (ms * 16 + qd * 4 + r) >> 1;
      int kpos = j * 16 + cp;
      if (o < 128) {
        v += ldin(phib, o, isbf);
        bf16_t hi = f2b(v);
        phiTh[(long)tile * 32768 + kpos * 128 + o] = hi;
        phiTl[(long)tile * 32768 + kpos * 128 + o] = f2b(v - b2f(hi));
      } else {
        v += ldin(gb, o - 128, isbf);
        gT[(long)tile * 32768 + (o - 128) * 256 + kpos] = f2b(v);
      }
    }
  }
}

// ---- K2: theta -> S (split-precision) -> softmax -> y -> Wy + BN + residual ----
__global__ __launch_bounds__(256) void k2(const void* xin, const bf16_t* thw2,
    const void* thb, const bf16_t* phiTh, const bf16_t* phiTl, const bf16_t* gT,
    const bf16_t* ww, const float* sc, const float* sh, void* outv, const int* flag) {
  int isbf = *flag;
  int wg = blockIdx.x;          // 128*32
  int tile = wg >> 5;
  int qb = wg & 31;             // pixel row within tile
  int bi = tile >> 4, t16 = tile & 15;
  int ty = t16 >> 2, tx = t16 & 3;
  long xbase = ((long)bi * 256) * 16384 + (long)(ty * 32 + qb) * 128 + tx * 32;

  // liveness-overlaid LDS (52224 B)
  __shared__ __align__(16) char smem[52224];
  bf16_t* sX  = (bf16_t*)smem;             // [32][520]  phases 1-2
  bf16_t* sTh = (bf16_t*)(smem + 33280);   // [32][136]  2-3
  bf16_t* sTl = (bf16_t*)(smem + 41984);   // [32][136]  2-3
  float*  sS  = (float*)smem;              // [32][260]  3-4
  bf16_t* sF  = (bf16_t*)(smem + 33280);   // [32][264]  4-5
  float*  sred= (float*)(smem + 50688);    // [256]      4
  bf16_t* sYh = (bf16_t*)smem;             // [32][136]  5-6
  bf16_t* sYl = (bf16_t*)(smem + 8704);    // [32][136]  5-6
  float*  sW  = (float*)(smem + 17408);    // [256][34]  6-7

  int tid = threadIdx.x, lane = tid & 63, wv = tid >> 6;
  int qd = lane >> 4, ln = lane & 15, kq = qd * 8;
  int Keff = isbf ? 256 : 512;

  // 1: stage X^T (hi|lo)
  for (int i = tid; i < 32 * 256; i += 256) {
    int c = i >> 5, q = i & 31;
    float v = ldin(xin, xbase + (long)c * 16384 + q, isbf);
    bf16_t hi = f2b(v);
    sX[q * LDK + c] = hi;
    if (!isbf) sX[q * LDK + 256 + c] = f2b(v - b2f(hi));
  }
  __syncthreads();

  // 2: theta = X^T @ thw^T + b  -> hi/lo
  #pragma unroll
  for (int t = 0; t < 4; ++t) {
    int tt = t * 4 + wv, ms = tt >> 3, ns = tt & 7;
    f32x4 z = {0.f, 0.f, 0.f, 0.f};
    f32x4 a = mm_acc(sX + (ms * 16 + ln) * LDK, thw2 + (ns * 16 + ln) * 512,
                     kq, Keff, z);
    float bias = ldin(thb, ns * 16 + ln, isbf);
    #pragma unroll
    for (int r = 0; r < 4; ++r) {
      float v = a[r] + bias;
      int m = ms * 16 + qd * 4 + r;
      bf16_t hi = f2b(v);
      sTh[m * LDT + ns * 16 + ln] = hi;
      sTl[m * LDT + ns * 16 + ln] = f2b(v - b2f(hi));
    }
  }
  __syncthreads();

  // 3: S = theta @ phi  (3-term split: th*pl + tl*ph + th*ph)
  const bf16_t* phh = phiTh + (long)tile * 32768;
  const bf16_t* phl = phiTl + (long)tile * 32768;
  #pragma unroll
  for (int t = 0; t < 8; ++t) {
    int tt = t * 4 + wv, ms = tt >> 4, ns = tt & 15;
    const bf16_t* Ah = sTh + (ms * 16 + ln) * LDT;
    const bf16_t* Al = sTl + (ms * 16 + ln) * LDT;
    const bf16_t* Bh = phh + (ns * 16 + ln) * 128;
    const bf16_t* Bl = phl + (ns * 16 + ln) * 128;
    f32x4 a = {0.f, 0.f, 0.f, 0.f};
    #pragma unroll
    for (int k = 0; k < 128; k += 32) {
      bf16x8 ah = *(const bf16x8*)(Ah + k + kq);
      bf16x8 al = *(const bf16x8*)(Al + k + kq);
      bf16x8 bh = *(const bf16x8*)(Bh + k + kq);
      bf16x8 bl = *(const bf16x8*)(Bl + k + kq);
      a = __builtin_amdgcn_mfma_f32_16x16x32_bf16(ah, bl, a, 0, 0, 0);
      a = __builtin_amdgcn_mfma_f32_16x16x32_bf16(al, bh, a, 0, 0, 0);
      a = __builtin_amdgcn_mfma_f32_16x16x32_bf16(ah, bh, a, 0, 0, 0);
    }
    #pragma unroll
    for (int r = 0; r < 4; ++r)
      sS[(ms * 16 + qd * 4 + r) * LDS_S + ns * 16 + ln] = a[r];
  }
  __syncthreads();

  // 4: softmax rows of S -> F (bf16)
  {
    int row = tid >> 3, seg = tid & 7;
    float* Sr = sS + row * LDS_S + seg * 32;
    float m = -1e30f;
    for (int jj = 0; jj < 32; ++jj) m = fmaxf(m, Sr[jj]);
    sred[row * 8 + seg] = m;
    __syncthreads();
    float rm = sred[row * 8];
    for (int k = 1; k < 8; ++k) rm = fmaxf(rm, sred[row * 8 + k]);
    __syncthreads();
    float sum = 0.f;
    for (int jj = 0; jj < 32; ++jj) { float e = __expf(Sr[jj] - rm); Sr[jj] = e; sum += e; }
    sred[row * 8 + seg] = sum;
    __syncthreads();
    float tot = 0.f;
    for (int k = 0; k < 8; ++k) tot += sred[row * 8 + k];
    float inv = 1.f / tot;
    for (int jj = 0; jj < 32; ++jj)
      sF[row * LDF + seg * 32 + jj] = f2b(Sr[jj] * inv);
  }
  __syncthreads();

  // 5: y = F @ g -> hi/lo
  const bf16_t* gt = gT + (long)tile * 32768;
  #pragma unroll
  for (int t = 0; t < 4; ++t) {
    int tt = t * 4 + wv, ms = tt >> 3, ns = tt & 7;
    f32x4 z = {0.f, 0.f, 0.f, 0.f};
    f32x4 a = mm_acc(sF + (ms * 16 + ln) * LDF, gt + (ns * 16 + ln) * 256, kq, 256, z);
    #pragma unroll
    for (int r = 0; r < 4; ++r) {
      int m = ms * 16 + qd * 4 + r;
      float v = a[r];
      bf16_t hi = f2b(v);
      sYh[m * LDT + ns * 16 + ln] = hi;
      sYl[m * LDT + ns * 16 + ln] = f2b(v - b2f(hi));
    }
  }
  __syncthreads();

  // 6: wy = Y @ ww^T (2-term split), BN scale/shift, transpose into sW
  #pragma unroll
  for (int t = 0; t < 8; ++t) {
    int tt = t * 4 + wv, ms = tt >> 4, ns = tt & 15;
    const bf16_t* Ah = sYh + (ms * 16 + ln) * LDT;
    const bf16_t* Al = sYl + (ms * 16 + ln) * LDT;
    const bf16_t* B  = ww + (ns * 16 + ln) * 128;
    f32x4 a = {0.f, 0.f, 0.f, 0.f};
    #pragma unroll
    for (int k = 0; k < 128; k += 32) {
      bf16x8 ah = *(const bf16x8*)(Ah + k + kq);
      bf16x8 al = *(const bf16x8*)(Al + k + kq);
      bf16x8 b  = *(const bf16x8*)(B + k + kq);
      a = __builtin_amdgcn_mfma_f32_16x16x32_bf16(al, b, a, 0, 0, 0);
      a = __builtin_amdgcn_mfma_f32_16x16x32_bf16(ah, b, a, 0, 0, 0);
    }
    int o = ns * 16 + ln;
    float s = sc[o], h = sh[o];
    #pragma unroll
    for (int r = 0; r < 4; ++r)
      sW[o * LDQ + ms * 16 + qd * 4 + r] = a[r] * s + h;
  }
  __syncthreads();

  // 7: out = wy + x (coalesced)
  long outbase = (long)tile * 262144 + (long)qb * 32;
  for (int i = tid; i < 256 * 32; i += 256) {
    int o = i >> 5, q = i & 31;
    float v = sW[o * LDQ + q] + ldin(xin, xbase + (long)o * 16384 + q, isbf);
    long oi = outbase + (long)o * 1024 + q;
    if (isbf) ((bf16_t*)outv)[oi] = f2b(v);
    else      ((float*)outv)[oi] = v;
  }
}

extern "C" void kernel_launch(void* const* d_in, const int* in_sizes, int n_in,
                              void* d_out, int out_size, void* d_ws, size_t ws_size,
                              hipStream_t stream) {
  (void)in_sizes; (void)n_in; (void)out_size; (void)ws_size;
  const void* x    = d_in[0];
  const void* thwf = d_in[1];
  const void* thb  = d_in[2];
  const void* phw  = d_in[3];
  const void* phb  = d_in[4];
  const void* gwf  = d_in[5];
  const void* gbb  = d_in[6];
  const void* wwf  = d_in[7];
  const void* wb   = d_in[8];
  const void* gma  = d_in[9];
  const void* bta  = d_in[10];
  const void* mn   = d_in[11];
  const void* vr   = d_in[12];

  char* ws = (char*)d_ws;
  bf16_t* thw2 = (bf16_t*)(ws);                      // 131072 B  [128][512]
  bf16_t* wpg2 = (bf16_t*)(ws + 131072);             // 262144 B  [256][512]
  bf16_t* ww   = (bf16_t*)(ws + 393216);             // 65536 B   [256][128]
  float*  sc   = (float*)(ws + 458752);              // 1024 B
  float*  sh   = (float*)(ws + 459776);              // 1024 B
  int*    flag = (int*)(ws + 460800);                // 256 B
  bf16_t* phiTh= (bf16_t*)(ws + 461056);             // 8388608 B [tile][k][i]
  bf16_t* phiTl= (bf16_t*)(ws + 461056 + 8388608);   // 8388608 B
  bf16_t* gT   = (bf16_t*)(ws + 461056 + 16777216);  // 8388608 B [tile][i][k]

  kdetect<<<1, 256, 0, stream>>>((const unsigned int*)x, flag);
  k0<<<512, 256, 0, stream>>>(thwf, phw, gwf, wwf, wb, gma, bta, mn, vr,
                              thw2, wpg2, ww, sc, sh, flag);
  k1<<<2048, 256, 0, stream>>>(x, wpg2, phb, gbb, phiTh, phiTl, gT, flag);
  k2<<<4096, 256, 0, stream>>>(x, thw2, thb, phiTh, phiTl, gT, ww, sc, sh, d_out, flag);
}

// Round 3
// 869.909 us; speedup vs baseline: 1.1101x; 1.1101x over previous
//
#include <hip/hip_runtime.h>
#include <hip/hip_bf16.h>

typedef __bf16 bf16_t;
typedef __bf16 bf16x8 __attribute__((ext_vector_type(8)));
typedef float f32x4 __attribute__((ext_vector_type(4)));

#define LDA 264   // k1 X rows (256 + 8)
#define LDK 520   // fallback k2f X rows [hi|lo] + 8
#define LDT 136   // theta/y rows (128 + 8)
#define LDF 264   // F rows (256 + 8)
#define LDS_S 260 // S rows fp32 (fallback)
#define LDQ 34    // wyT rows fp32 (fallback)

__device__ __forceinline__ float ldin(const void* p, long i, int isbf) {
  if (isbf) {
    unsigned short u = ((const unsigned short*)p)[i];
    unsigned int w = ((unsigned int)u) << 16;
    float f; __builtin_memcpy(&f, &w, 4); return f;
  }
  return ((const float*)p)[i];
}

__device__ __forceinline__ bf16_t f2b(float f) {
  unsigned int u; __builtin_memcpy(&u, &f, 4);
  u += 0x7FFFu + ((u >> 16) & 1u);
  unsigned short h = (unsigned short)(u >> 16);
  bf16_t r; __builtin_memcpy(&r, &h, 2); return r;
}

__device__ __forceinline__ float b2f(bf16_t b) {
  unsigned short h; __builtin_memcpy(&h, &b, 2);
  unsigned int u = ((unsigned int)h) << 16;
  float f; __builtin_memcpy(&f, &u, 4); return f;
}

__device__ __forceinline__ f32x4 mfma(bf16x8 a, bf16x8 b, f32x4 c) {
  return __builtin_amdgcn_mfma_f32_16x16x32_bf16(a, b, c, 0, 0, 0);
}

// D(16x16)+=A(16xK)*B(Kx16). A rows [m][K] (ptr at row m0+ln), B rows [n][K]
// (ptr at row n0+ln). kq=(lane>>4)*8. D: n=lane&15, m=(lane>>4)*4+reg.
__device__ __forceinline__ f32x4 mm_acc(const bf16_t* A, const bf16_t* B, int kq,
                                        int K, f32x4 acc) {
  for (int k = 0; k < K; k += 32) {
    bf16x8 a = *(const bf16x8*)(A + k + kq);
    bf16x8 b = *(const bf16x8*)(B + k + kq);
    acc = mfma(a, b, acc);
  }
  return acc;
}

// ---- dtype detector ----
__global__ void kdetect(const unsigned int* x, int* flag) {
  __shared__ int cnt;
  if (threadIdx.x == 0) cnt = 0;
  __syncthreads();
  int local = 0;
  for (int k = 0; k < 4; ++k) {
    unsigned int u = x[threadIdx.x * 4 + k];
    unsigned int e = (u >> 7) & 0xFFu;
    if (e >= 116u && e <= 133u) local++;
  }
  atomicAdd(&cnt, local);
  __syncthreads();
  if (threadIdx.x == 0) *flag = (cnt > 512) ? 1 : 0;
}

// ---- K0: weight conversion + BN folding (thw2 doubled for fallback path) ----
__global__ void k0(const void* thw_f, const void* phw, const void* gw, const void* ww_f,
                   const void* wb, const void* gma, const void* bta, const void* mean,
                   const void* var, bf16_t* thwb, bf16_t* phwb, bf16_t* gwb, bf16_t* wwb,
                   bf16_t* thw2, float* sc, float* sh, const int* flag) {
  int isbf = *flag;
  int i = blockIdx.x * 256 + threadIdx.x;   // 128 blocks -> 32768 threads
  thwb[i] = f2b(ldin(thw_f, i, isbf));
  phwb[i] = f2b(ldin(phw, i, isbf));
  gwb[i]  = f2b(ldin(gw, i, isbf));
  wwb[i]  = f2b(ldin(ww_f, i, isbf));
  { // doubled theta weights [o][w|w] for fallback K=512 path (bug from r2 fixed)
    int o = i >> 8, c = i & 255;
    bf16_t b = f2b(ldin(thw_f, (long)o * 256 + c, isbf));
    thw2[o * 512 + c] = b;
    thw2[o * 512 + 256 + c] = b;
  }
  if (i < 256) {
    float s = ldin(gma, i, isbf) * rsqrtf(ldin(var, i, isbf) + 1e-5f);
    sc[i] = s;
    sh[i] = (ldin(wb, i, isbf) - ldin(mean, i, isbf)) * s + ldin(bta, i, isbf);
  }
}

// ---- K1: theta + phi + g convs (shared A), register maxpool, hi/lo stores ----
__global__ __launch_bounds__(256) void k1(const void* xin, const bf16_t* thwb,
    const bf16_t* phwb, const bf16_t* gwb, const void* thb, const void* phb,
    const void* gbb, bf16_t* thetaH, bf16_t* thetaL, bf16_t* phiH, bf16_t* phiL,
    bf16_t* gT, const int* flag, int haveT) {
  int isbf = *flag;
  int wg = blockIdx.x;          // 128*16
  int tile = wg >> 4, j = wg & 15;
  int bi = tile >> 4, t16 = tile & 15, ty = t16 >> 2, tx = t16 & 3;
  long xb = (long)bi * 256 * 16384 + (long)(ty * 32 + 2 * j) * 128 + tx * 32;

  __shared__ __align__(16) bf16_t sX[64 * LDA];   // X^T [64 px][256 c]

  int tid = threadIdx.x, lane = tid & 63, wv = tid >> 6;
  int qd = lane >> 4, ln = lane & 15, kq = qd * 8;

  for (int i = tid; i < 64 * 256; i += 256) {
    int c = i >> 6, m = i & 63;
    sX[m * LDA + c] =
        f2b(ldin(xin, xb + (long)c * 16384 + (m >> 5) * 128 + (m & 31), isbf));
  }
  __syncthreads();

  f32x4 accT[4][2], accP[4][2], accG[4][2];
  for (int mb = 0; mb < 4; ++mb) {
    const bf16_t* A = sX + (mb * 16 + ln) * LDA;
    bf16x8 af[8];
    #pragma unroll
    for (int c = 0; c < 8; ++c) af[c] = *(const bf16x8*)(A + c * 32 + kq);
    #pragma unroll
    for (int h = 0; h < 2; ++h) {
      int nt = wv + h * 4;
      const bf16_t* Bt = thwb + (nt * 16 + ln) * 256;
      const bf16_t* Bp = phwb + (nt * 16 + ln) * 256;
      const bf16_t* Bg = gwb + (nt * 16 + ln) * 256;
      f32x4 at = {0.f,0.f,0.f,0.f}, ap = {0.f,0.f,0.f,0.f}, ag = {0.f,0.f,0.f,0.f};
      #pragma unroll
      for (int c = 0; c < 8; ++c) {
        int ko = c * 32 + kq;
        at = mfma(af[c], *(const bf16x8*)(Bt + ko), at);
        ap = mfma(af[c], *(const bf16x8*)(Bp + ko), ap);
        ag = mfma(af[c], *(const bf16x8*)(Bg + ko), ag);
      }
      accT[mb][h] = at; accP[mb][h] = ap; accG[mb][h] = ag;
    }
  }

  // theta store (hi/lo), pix = j*64 + m, m = mb*16 + qd*4 + r
  if (haveT) {
    for (int mb = 0; mb < 4; ++mb)
      #pragma unroll
      for (int h = 0; h < 2; ++h) {
        int o = (wv + h * 4) * 16 + ln;
        float bias = ldin(thb, o, isbf);
        #pragma unroll
        for (int r = 0; r < 4; ++r) {
          int pix = j * 64 + mb * 16 + qd * 4 + r;
          float v = accT[mb][h][r] + bias;
          bf16_t hi = f2b(v);
          long a = (long)tile * 131072 + (long)pix * 128 + o;
          thetaH[a] = hi;
          thetaL[a] = f2b(v - b2f(hi));
        }
      }
  }

  // register 2x2 maxpool: cols (r,r+1) pairs, rows via mb partner mb+2
  for (int mb2 = 0; mb2 < 2; ++mb2)
    #pragma unroll
    for (int h = 0; h < 2; ++h) {
      int o = (wv + h * 4) * 16 + ln;
      float pb = ldin(phb, o, isbf), gb2 = ldin(gbb, o, isbf);
      #pragma unroll
      for (int r = 0; r < 4; r += 2) {
        float v = fmaxf(fmaxf(accP[mb2][h][r], accP[mb2][h][r + 1]),
                        fmaxf(accP[mb2 + 2][h][r], accP[mb2 + 2][h][r + 1]));
        float u = fmaxf(fmaxf(accG[mb2][h][r], accG[mb2][h][r + 1]),
                        fmaxf(accG[mb2 + 2][h][r], accG[mb2 + 2][h][r + 1]));
        int cp = mb2 * 8 + qd * 2 + (r >> 1);
        int kpos = j * 16 + cp;
        float pv = v + pb;
        bf16_t hi = f2b(pv);
        phiH[(long)tile * 32768 + kpos * 128 + o] = hi;
        phiL[(long)tile * 32768 + kpos * 128 + o] = f2b(pv - b2f(hi));
        gT[(long)tile * 32768 + (long)o * 256 + kpos] = f2b(u + gb2);
      }
    }
}

// ---- K2 (lean): S from ws-theta, register softmax, y, wy+BN+residual ----
__global__ __launch_bounds__(256) void k2(const void* xin, const bf16_t* thetaH,
    const bf16_t* thetaL, const bf16_t* phiH, const bf16_t* phiL, const bf16_t* gT,
    const bf16_t* wwb, const float* sc, const float* sh, void* outv, const int* flag) {
  int isbf = *flag;
  int wg = blockIdx.x;          // 128*32
  int tile = wg >> 5, qb = wg & 31;
  int bi = tile >> 4, t16 = tile & 15, ty = t16 >> 2, tx = t16 & 3;
  long xrow = (long)bi * 256 * 16384 + (long)(ty * 32 + qb) * 128 + tx * 32;

  __shared__ __align__(16) bf16_t sF[32 * LDF];   // 16896 B
  __shared__ __align__(16) bf16_t sY[32 * LDT];   // 8704 B
  __shared__ float sredM[64], sredS[64];

  int tid = threadIdx.x, lane = tid & 63, wv = tid >> 6;
  int qd = lane >> 4, ln = lane & 15, kq = qd * 8;
  int ms = wv >> 1, half = wv & 1;

  // theta A-frags straight from ws (L2/L3)
  const bf16_t* TH = thetaH + (long)tile * 131072 + (long)(qb * 32 + ms * 16 + ln) * 128;
  const bf16_t* TL = thetaL + (long)tile * 131072 + (long)(qb * 32 + ms * 16 + ln) * 128;
  bf16x8 Ah[4], Al[4];
  #pragma unroll
  for (int c = 0; c < 4; ++c) {
    Ah[c] = *(const bf16x8*)(TH + c * 32 + kq);
    Al[c] = *(const bf16x8*)(TL + c * 32 + kq);
  }

  // S = theta @ phi (3-term split), wave covers half the n-range
  f32x4 S[8];
  const bf16_t* PH = phiH + (long)tile * 32768;
  const bf16_t* PL = phiL + (long)tile * 32768;
  #pragma unroll
  for (int t = 0; t < 8; ++t) {
    int ns = half * 8 + t;
    const bf16_t* Bh = PH + (ns * 16 + ln) * 128;
    const bf16_t* Bl = PL + (ns * 16 + ln) * 128;
    f32x4 a = {0.f, 0.f, 0.f, 0.f};
    #pragma unroll
    for (int c = 0; c < 4; ++c) {
      int ko = c * 32 + kq;
      bf16x8 bh = *(const bf16x8*)(Bh + ko);
      bf16x8 bl = *(const bf16x8*)(Bl + ko);
      a = mfma(Ah[c], bl, a);
      a = mfma(Al[c], bh, a);
      a = mfma(Ah[c], bh, a);
    }
    S[t] = a;
  }

  // register softmax: shfl over 16-lane group + 2-way LDS exchange
  float Mr[4], Sr[4], inv4[4];
  #pragma unroll
  for (int r = 0; r < 4; ++r) {
    float m = S[0][r];
    #pragma unroll
    for (int t = 1; t < 8; ++t) m = fmaxf(m, S[t][r]);
    #pragma unroll
    for (int d = 1; d < 16; d <<= 1) m = fmaxf(m, __shfl_xor(m, d, 64));
    Mr[r] = m;
  }
  if (ln == 0) {
    #pragma unroll
    for (int r = 0; r < 4; ++r) sredM[(ms * 16 + qd * 4 + r) * 2 + half] = Mr[r];
  }
  __syncthreads();
  #pragma unroll
  for (int r = 0; r < 4; ++r)
    Mr[r] = fmaxf(Mr[r], sredM[(ms * 16 + qd * 4 + r) * 2 + (half ^ 1)]);
  #pragma unroll
  for (int r = 0; r < 4; ++r) {
    float s = 0.f;
    #pragma unroll
    for (int t = 0; t < 8; ++t) {
      float e = __expf(S[t][r] - Mr[r]); S[t][r] = e; s += e;
    }
    #pragma unroll
    for (int d = 1; d < 16; d <<= 1) s += __shfl_xor(s, d, 64);
    Sr[r] = s;
  }
  if (ln == 0) {
    #pragma unroll
    for (int r = 0; r < 4; ++r) sredS[(ms * 16 + qd * 4 + r) * 2 + half] = Sr[r];
  }
  __syncthreads();
  #pragma unroll
  for (int r = 0; r < 4; ++r)
    inv4[r] = 1.f / (Sr[r] + sredS[(ms * 16 + qd * 4 + r) * 2 + (half ^ 1)]);

  // F -> LDS (D-layout positions)
  #pragma unroll
  for (int t = 0; t < 8; ++t) {
    int n = (half * 8 + t) * 16 + ln;
    #pragma unroll
    for (int r = 0; r < 4; ++r)
      sF[(ms * 16 + qd * 4 + r) * LDF + n] = f2b(S[t][r] * inv4[r]);
  }
  __syncthreads();

  // y = F @ g
  const bf16_t* G = gT + (long)tile * 32768;
  f32x4 Y[4];
  #pragma unroll
  for (int t2 = 0; t2 < 4; ++t2) {
    int tt = t2 * 4 + wv, ms2 = tt >> 3, ns = tt & 7;
    const bf16_t* A = sF + (ms2 * 16 + ln) * LDF;
    const bf16_t* B = G + (ns * 16 + ln) * 256;
    f32x4 a = {0.f, 0.f, 0.f, 0.f};
    #pragma unroll
    for (int c = 0; c < 8; ++c) {
      int ko = c * 32 + kq;
      a = mfma(*(const bf16x8*)(A + ko), *(const bf16x8*)(B + ko), a);
    }
    Y[t2] = a;
  }
  #pragma unroll
  for (int t2 = 0; t2 < 4; ++t2) {
    int tt = t2 * 4 + wv, ms2 = tt >> 3, ns = tt & 7;
    #pragma unroll
    for (int r = 0; r < 4; ++r)
      sY[(ms2 * 16 + qd * 4 + r) * LDT + ns * 16 + ln] = f2b(Y[t2][r]);
  }
  __syncthreads();

  // wy = Y @ ww^T, BN, residual, direct store
  #pragma unroll
  for (int t3 = 0; t3 < 8; ++t3) {
    int tt = t3 * 4 + wv, ms3 = tt >> 4, ns = tt & 15;
    const bf16_t* A = sY + (ms3 * 16 + ln) * LDT;
    const bf16_t* B = wwb + (ns * 16 + ln) * 128;
    f32x4 a = {0.f, 0.f, 0.f, 0.f};
    #pragma unroll
    for (int c = 0; c < 4; ++c) {
      int ko = c * 32 + kq;
      a = mfma(*(const bf16x8*)(A + ko), *(const bf16x8*)(B + ko), a);
    }
    int o = ns * 16 + ln;
    float s = sc[o], hh = sh[o];
    int m0 = ms3 * 16 + qd * 4;
    long xi = xrow + (long)o * 16384 + m0;
    long oi = (long)tile * 262144 + (long)o * 1024 + qb * 32 + m0;
    #pragma unroll
    for (int r = 0; r < 4; ++r) {
      float v = a[r] * s + hh + ldin(xin, xi + r, isbf);
      if (isbf) ((bf16_t*)outv)[oi + r] = f2b(v);
      else      ((float*)outv)[oi + r] = v;
    }
  }
}

// ---- K2f: round-2 fallback (used only if ws too small for theta arrays) ----
__global__ __launch_bounds__(256) void k2f(const void* xin, const bf16_t* thw2,
    const void* thb, const bf16_t* phiTh, const bf16_t* phiTl, const bf16_t* gT,
    const bf16_t* ww, const float* sc, const float* sh, void* outv, const int* flag) {
  int isbf = *flag;
  int wg = blockIdx.x;
  int tile = wg >> 5, qb = wg & 31;
  int bi = tile >> 4, t16 = tile & 15, ty = t16 >> 2, tx = t16 & 3;
  long xbase = ((long)bi * 256) * 16384 + (long)(ty * 32 + qb) * 128 + tx * 32;

  __shared__ __align__(16) char smem[52224];
  bf16_t* sX  = (bf16_t*)smem;
  bf16_t* sTh = (bf16_t*)(smem + 33280);
  bf16_t* sTl = (bf16_t*)(smem + 41984);
  float*  sS  = (float*)smem;
  bf16_t* sF  = (bf16_t*)(smem + 33280);
  float*  sred= (float*)(smem + 50688);
  bf16_t* sYh = (bf16_t*)smem;
  bf16_t* sYl = (bf16_t*)(smem + 8704);
  float*  sW  = (float*)(smem + 17408);

  int tid = threadIdx.x, lane = tid & 63, wv = tid >> 6;
  int qd = lane >> 4, ln = lane & 15, kq = qd * 8;
  int Keff = isbf ? 256 : 512;

  for (int i = tid; i < 32 * 256; i += 256) {
    int c = i >> 5, q = i & 31;
    float v = ldin(xin, xbase + (long)c * 16384 + q, isbf);
    bf16_t hi = f2b(v);
    sX[q * LDK + c] = hi;
    if (!isbf) sX[q * LDK + 256 + c] = f2b(v - b2f(hi));
  }
  __syncthreads();

  #pragma unroll
  for (int t = 0; t < 4; ++t) {
    int tt = t * 4 + wv, ms = tt >> 3, ns = tt & 7;
    f32x4 z = {0.f, 0.f, 0.f, 0.f};
    f32x4 a = mm_acc(sX + (ms * 16 + ln) * LDK, thw2 + (ns * 16 + ln) * 512,
                     kq, Keff, z);
    float bias = ldin(thb, ns * 16 + ln, isbf);
    #pragma unroll
    for (int r = 0; r < 4; ++r) {
      float v = a[r] + bias;
      int m = ms * 16 + qd * 4 + r;
      bf16_t hi = f2b(v);
      sTh[m * LDT + ns * 16 + ln] = hi;
      sTl[m * LDT + ns * 16 + ln] = f2b(v - b2f(hi));
    }
  }
  __syncthreads();

  const bf16_t* phh = phiTh + (long)tile * 32768;
  const bf16_t* phl = phiTl + (long)tile * 32768;
  #pragma unroll
  for (int t = 0; t < 8; ++t) {
    int tt = t * 4 + wv, ms = tt >> 4, ns = tt & 15;
    const bf16_t* Ah = sTh + (ms * 16 + ln) * LDT;
    const bf16_t* Al = sTl + (ms * 16 + ln) * LDT;
    const bf16_t* Bh = phh + (ns * 16 + ln) * 128;
    const bf16_t* Bl = phl + (ns * 16 + ln) * 128;
    f32x4 a = {0.f, 0.f, 0.f, 0.f};
    #pragma unroll
    for (int k = 0; k < 128; k += 32) {
      bf16x8 ah = *(const bf16x8*)(Ah + k + kq);
      bf16x8 al = *(const bf16x8*)(Al + k + kq);
      bf16x8 bh = *(const bf16x8*)(Bh + k + kq);
      bf16x8 bl = *(const bf16x8*)(Bl + k + kq);
      a = mfma(ah, bl, a); a = mfma(al, bh, a); a = mfma(ah, bh, a);
    }
    #pragma unroll
    for (int r = 0; r < 4; ++r)
      sS[(ms * 16 + qd * 4 + r) * LDS_S + ns * 16 + ln] = a[r];
  }
  __syncthreads();

  {
    int row = tid >> 3, seg = tid & 7;
    float* Srow = sS + row * LDS_S + seg * 32;
    float m = -1e30f;
    for (int jj = 0; jj < 32; ++jj) m = fmaxf(m, Srow[jj]);
    sred[row * 8 + seg] = m;
    __syncthreads();
    float rm = sred[row * 8];
    for (int k = 1; k < 8; ++k) rm = fmaxf(rm, sred[row * 8 + k]);
    __syncthreads();
    float sum = 0.f;
    for (int jj = 0; jj < 32; ++jj) { float e = __expf(Srow[jj] - rm); Srow[jj] = e; sum += e; }
    sred[row * 8 + seg] = sum;
    __syncthreads();
    float tot = 0.f;
    for (int k = 0; k < 8; ++k) tot += sred[row * 8 + k];
    float inv = 1.f / tot;
    for (int jj = 0; jj < 32; ++jj)
      sF[row * LDF + seg * 32 + jj] = f2b(Srow[jj] * inv);
  }
  __syncthreads();

  const bf16_t* gt = gT + (long)tile * 32768;
  #pragma unroll
  for (int t = 0; t < 4; ++t) {
    int tt = t * 4 + wv, ms = tt >> 3, ns = tt & 7;
    f32x4 z = {0.f, 0.f, 0.f, 0.f};
    f32x4 a = mm_acc(sF + (ms * 16 + ln) * LDF, gt + (ns * 16 + ln) * 256, kq, 256, z);
    #pragma unroll
    for (int r = 0; r < 4; ++r) {
      int m = ms * 16 + qd * 4 + r;
      float v = a[r];
      bf16_t hi = f2b(v);
      sYh[m * LDT + ns * 16 + ln] = hi;
      sYl[m * LDT + ns * 16 + ln] = f2b(v - b2f(hi));
    }
  }
  __syncthreads();

  #pragma unroll
  for (int t = 0; t < 8; ++t) {
    int tt = t * 4 + wv, ms = tt >> 4, ns = tt & 15;
    const bf16_t* Ah = sYh + (ms * 16 + ln) * LDT;
    const bf16_t* Al = sYl + (ms * 16 + ln) * LDT;
    const bf16_t* B  = ww + (ns * 16 + ln) * 128;
    f32x4 a = {0.f, 0.f, 0.f, 0.f};
    #pragma unroll
    for (int k = 0; k < 128; k += 32) {
      bf16x8 ah = *(const bf16x8*)(Ah + k + kq);
      bf16x8 al = *(const bf16x8*)(Al + k + kq);
      bf16x8 b  = *(const bf16x8*)(B + k + kq);
      a = mfma(al, b, a); a = mfma(ah, b, a);
    }
    int o = ns * 16 + ln;
    float s = sc[o], h = sh[o];
    #pragma unroll
    for (int r = 0; r < 4; ++r)
      sW[o * LDQ + ms * 16 + qd * 4 + r] = a[r] * s + h;
  }
  __syncthreads();

  long outbase = (long)tile * 262144 + (long)qb * 32;
  for (int i = tid; i < 256 * 32; i += 256) {
    int o = i >> 5, q = i & 31;
    float v = sW[o * LDQ + q] + ldin(xin, xbase + (long)o * 16384 + q, isbf);
    long oi = outbase + (long)o * 1024 + q;
    if (isbf) ((bf16_t*)outv)[oi] = f2b(v);
    else      ((float*)outv)[oi] = v;
  }
}

extern "C" void kernel_launch(void* const* d_in, const int* in_sizes, int n_in,
                              void* d_out, int out_size, void* d_ws, size_t ws_size,
                              hipStream_t stream) {
  (void)in_sizes; (void)n_in; (void)out_size;
  const void* x    = d_in[0];
  const void* thwf = d_in[1];
  const void* thb  = d_in[2];
  const void* phw  = d_in[3];
  const void* phb  = d_in[4];
  const void* gwf  = d_in[5];
  const void* gbb  = d_in[6];
  const void* wwf  = d_in[7];
  const void* wb   = d_in[8];
  const void* gma  = d_in[9];
  const void* bta  = d_in[10];
  const void* mn   = d_in[11];
  const void* vr   = d_in[12];

  char* ws = (char*)d_ws;
  bf16_t* thwb = (bf16_t*)(ws);                    // 65536
  bf16_t* phwb = (bf16_t*)(ws + 65536);            // 65536
  bf16_t* gwb  = (bf16_t*)(ws + 131072);           // 65536
  bf16_t* wwb  = (bf16_t*)(ws + 196608);           // 65536
  bf16_t* thw2 = (bf16_t*)(ws + 262144);           // 131072 (fallback only)
  float*  sc   = (float*)(ws + 393216);            // 1024
  float*  sh   = (float*)(ws + 394240);            // 1024
  int*    flag = (int*)(ws + 395264);              // 256
  bf16_t* phiH = (bf16_t*)(ws + 395520);           // 8388608  [tile][k][i]
  bf16_t* phiL = (bf16_t*)(ws + 395520 + 8388608);
  bf16_t* gT   = (bf16_t*)(ws + 395520 + 16777216);// 8388608  [tile][i][k]
  bf16_t* thH  = (bf16_t*)(ws + 25561344);         // 33554432 [tile][pix][128]
  bf16_t* thL  = (bf16_t*)(ws + 25561344 + 33554432);
  int haveT = (ws_size >= (size_t)92670208) ? 1 : 0;

  kdetect<<<1, 256, 0, stream>>>((const unsigned int*)x, flag);
  k0<<<128, 256, 0, stream>>>(thwf, phw, gwf, wwf, wb, gma, bta, mn, vr,
                              thwb, phwb, gwb, wwb, thw2, sc, sh, flag);
  k1<<<2048, 256, 0, stream>>>(x, thwb, phwb, gwb, thb, phb, gbb,
                               thH, thL, phiH, phiL, gT, flag, haveT);
  if (haveT)
    k2<<<4096, 256, 0, stream>>>(x, thH, thL, phiH, phiL, gT, wwb, sc, sh,
                                 d_out, flag);
  else
    k2f<<<4096, 256, 0, stream>>>(x, thw2, thb, phiH, phiL, gT, wwb, sc, sh,
                                  d_out, flag);
}